// Round 10
// baseline (146.682 us; speedup 1.0000x reference)
//
#include <hip/hip_runtime.h>
#include <hip/hip_bf16.h>
#include <stdint.h>

#define P    300
#define HID  128
#define NG   1000
#define NTL  19          // 16-node tiles (304 rows, 300 valid)

typedef __attribute__((ext_vector_type(8))) short bf16x8;
typedef __attribute__((ext_vector_type(4))) short bf16x4;
typedef __attribute__((ext_vector_type(4))) float f32x4;

// Swizzled bf16 W^T. Slot fkey holds weights for column perm(fkey):
// W2 (pass0): perm(fkey) = u*32 + 2*(fkey&15) + ((fkey>>4)&1), u=fkey>>5
//   -> each wave's computed feature IS its physical store position, so
//      h2's physical layout is natural and W3 (pass1) is natural.
// chunk(fkey,kc) at slot fkey*16 + (kc ^ (fkey&15)).
__device__ short g_wsw[2 * HID * HID];

__device__ __forceinline__ short f2bf(float f) {
    union { float f; uint32_t u; } v; v.f = f;
    uint32_t r = v.u + 0x7fffu + ((v.u >> 16) & 1u);   // RNE
    return (short)(r >> 16);
}
__device__ __forceinline__ float bf2f(short s) {
    union { uint32_t u; float f; } v; v.u = ((uint32_t)(uint16_t)s) << 16;
    return v.f;
}
__device__ __forceinline__ uint32_t pkbf2(float a, float b) {   // low=a, high=b
    union { __hip_bfloat162 h; uint32_t u; } cv;
    cv.h = __float22bfloat162_rn(float2{a, b});
    return cv.u;
}
__device__ __forceinline__ float unpk(int v, int ft) {
    return bf2f((short)(ft ? (((uint32_t)v) >> 16) : (v & 0xffff)));
}

// K=16 bf16 MFMA as cross-lane "selector": A = constant 0/1 matrix, B =
// bf16-packed G-tile, C accumulates neighbor rows in f32. Layout match:
// C-frag of 16x16x32 (row=4q+reg, col=lm) == B-frag of 16x16x16
// (k=4q+j, col=lm) -> pack is 2 pkbf2, no shuffles. Verified r5-r9.
__device__ __forceinline__ f32x4 mfma16(bf16x4 a, bf16x4 b, f32x4 c) {
#if __has_builtin(__builtin_amdgcn_mfma_f32_16x16x16bf16_1k)
    return __builtin_amdgcn_mfma_f32_16x16x16bf16_1k(a, b, c, 0, 0, 0);
#else
    asm("v_mfma_f32_16x16x16_bf16 %0, %1, %2, %0" : "+v"(c) : "v"(a), "v"(b));
    return c;
#endif
}

__global__ __launch_bounds__(256) void k_prep(const float* __restrict__ W2,
                                              const float* __restrict__ W3) {
    int b = blockIdx.x;                       // 16 blocks
    const bool perm = (b < 8);
    const float* W = perm ? W2 : W3;
    short* dst = g_wsw + (perm ? 0 : HID * HID);
    int t    = (b & 7) * 256 + threadIdx.x;   // 0..2047 chunks
    int fkey = t >> 4;
    int kc   = t & 15;
    int fsrc;
    if (perm) {
        int u = fkey >> 5, ft = (fkey >> 4) & 1, l = fkey & 15;
        fsrc = u * 32 + 2 * l + ft;
    } else fsrc = fkey;
    bf16x8 o;
    #pragma unroll
    for (int j = 0; j < 8; ++j)
        o[j] = f2bf(W[(kc * 8 + j) * HID + fsrc]);
    *(bf16x8*)&dst[(fkey * 16 + (kc ^ (fkey & 15))) * 8] = o;
}

// One GCN layer; 8 waves = 2 NODE groups x 4 waves, each wave 2 ft-tiles.
// Rationale (r9 post-mortem): r9's 1-ft/8-wave layout had every wave read
// every A-fragment (8x redundancy) -> ~70% LDS-pipe utilization, the
// shared ceiling that kept per-graph time at ~13.6 us. 2-ft/wave reads
// each A-fragment ONCE for both MFMAs (4x redundancy, LDS -34%); the
// node-split keeps 8 waves. Boundary tiles duplicate-computed (+21%
// MFMA on a 26%-utilized pipe).
// Schedule (5 barriers/pass, both groups aligned; base = grp?10:0):
//   pro  g0: read {18->z299, 9->bq9p}   g1: read {0->z0, 8->bqM, 9->Gh/bqH}
//   j1..j4: read {base+2j-2, base+2j-1}; BARRIER; epi/store 2 tiles
//           (g0 j1: single epi of tile 0)
//   j5:     read {base+8}; BARRIER; epi/store {base+7, base+8}
// Race-proof, stores(j) vs reads(j+1) disjoint (union of both groups):
//   st(j1)={0,9,10} rd(j2)={2,3,12,13}; st(j2)={1,2,11,12} rd(j3)={4,5,
//   14,15}; st(j3)={3,4,13,14} rd(j4)={6,7,16,17}; st(j4)={5,6,15,16}
//   rd(j5)={8,18}; st(j5)={7,8,17,18} rd=none. Same-period rd/st are
//   separated by the barrier. Pro reads precede all stores.
// Wraps: tile0 vp0(q==0) = node299 = z299 (G18 r11, shfl 32+lm, bf16-rnd
// same as r0); tile18 vn3(q==2) = node0 = z0 (G0 r0, shfl lm). Sp x bq
// into tile0 / Sb row12 into tile18 contribute the ZERO pad rows -> safe.
template<int POOL>
__device__ __forceinline__ void run_pass(short* __restrict__ buf,
                                         const short* __restrict__ wbase,
                                         const float* __restrict__ bias,
                                         float* __restrict__ pool, int tid) {
    const int lane = tid & 63, wv = tid >> 6;
    const int grp = wv >> 2, w4 = wv & 3;
    const int q = lane >> 4, lm = lane & 15;
    const int ftg0 = w4 * 2;
    bf16x8 wf[2][4];
    #pragma unroll
    for (int ft = 0; ft < 2; ++ft) {
        int fkey = (ftg0 + ft) * 16 + lm;
        #pragma unroll
        for (int kk = 0; kk < 4; ++kk)
            wf[ft][kk] = *(const bf16x8*)&wbase[(fkey * 16 + ((4 * kk + q) ^ lm)) * 8];
    }
    float biaf[2];
    #pragma unroll
    for (int ft = 0; ft < 2; ++ft)
        biaf[ft] = POOL ? bias[(ftg0 + ft) * 16 + lm] : bias[w4 * 32 + 2 * lm + ft];
    const int fpair = w4 * 32 + 2 * lm;       // even physical feature (pass0)
    const int kcs = fpair >> 3, offs = fpair & 7;

    // selector A-fragments: A[m=lm][k=4q+j], entries bf16 1.0
    const short ONE = (short)0x3F80;
    bf16x4 Sb = {0, 0, 0, 0}, Sp = {0, 0, 0, 0}, Sn = {0, 0, 0, 0};
    #pragma unroll
    for (int j = 0; j < 4; ++j) {
        const int k = 4 * q + j;
        if (((lm & 3) == 0 && k == lm - 1) || ((lm & 3) == 3 && k == lm + 1))
            Sb[j] = ONE;
        if (lm == 0  && k == 15) Sp[j] = ONE;
        if (lm == 15 && k == 0 ) Sn[j] = ONE;
    }

    float psum[2] = {0.f, 0.f};
    float z[2];                               // wrap values (bf16-rounded)

    auto mfma_tile = [&](int t, f32x4 (&G)[2]) {
        const short* tb = buf + t * 2048;
        G[0] = f32x4{0.f, 0.f, 0.f, 0.f};
        G[1] = f32x4{0.f, 0.f, 0.f, 0.f};
        #pragma unroll
        for (int kk = 0; kk < 4; ++kk) {
            bf16x8 af = *(const bf16x8*)&tb[(lm * 16 + ((4 * kk + q) ^ lm)) * 8];
            G[0] = __builtin_amdgcn_mfma_f32_16x16x32_bf16(af, wf[0][kk], G[0], 0, 0, 0);
            G[1] = __builtin_amdgcn_mfma_f32_16x16x32_bf16(af, wf[1][kk], G[1], 0, 0, 0);
        }
    };
    auto pack = [&](const f32x4 (&G)[2], bf16x4 (&d)[2]) {
        #pragma unroll
        for (int ft = 0; ft < 2; ++ft) {
            union { bf16x4 v; uint32_t u[2]; } pk;
            pk.u[0] = pkbf2(G[ft][0], G[ft][1]);
            pk.u[1] = pkbf2(G[ft][2], G[ft][3]);
            d[ft] = pk.v;
        }
    };
    auto store_rows = [&](int T, float (&o)[2][4]) {
        #pragma unroll
        for (int i = 0; i < 4; ++i) {
            int node = T * 16 + q * 4 + i;
            *(uint32_t*)&buf[(node * 16 + (kcs ^ (node & 15))) * 8 + offs] =
                pkbf2(o[0][i], o[1][i]);
        }
    };
    auto accum = [&](float (&o)[2][4]) {
        #pragma unroll
        for (int ft = 0; ft < 2; ++ft)
            psum[ft] += o[ft][0] + o[ft][1] + o[ft][2] + o[ft][3];
    };

    // mode: 0 normal; 1 tile0 (skip Sp, +z at q==0/row0); 2 tile18
    // (skip Sn, +z at q==2/row11; caller guards q<3).
    auto epi = [&](const f32x4 (&E)[2], const bf16x4 (&bT)[2],
                   const bf16x4 (&bP)[2], const bf16x4 (&bN)[2],
                   int mode, float (&o)[2][4]) {
        #pragma unroll
        for (int ft = 0; ft < 2; ++ft) {
            f32x4 C = {0.f, 0.f, 0.f, 0.f};
            C = mfma16(Sb, bT[ft], C);
            if (mode != 1) C = mfma16(Sp, bP[ft], C);
            if (mode != 2) C = mfma16(Sn, bN[ft], C);
            const float s0 = E[ft][0] + E[ft][1];
            const float s2 = E[ft][2] + E[ft][3];
            float t0 = C[0] + s0;            // prev + G0 + G1
            float t1 = s0 + E[ft][2];
            float t2 = E[ft][1] + s2;
            float t3 = s2 + C[3];            // G2 + G3 + next
            if (mode == 1) t0 += (q == 0) ? z[ft] : 0.f;   // node299 wrap
            if (mode == 2) t3 += (q == 2) ? z[ft] : 0.f;   // node0 wrap
            float v0 = fmaf(t0, 1.f / 3.f, biaf[ft]);
            float v1 = fmaf(t1, 1.f / 3.f, biaf[ft]);
            float v2 = fmaf(t2, 1.f / 3.f, biaf[ft]);
            float v3 = fmaf(t3, 1.f / 3.f, biaf[ft]);
            o[ft][0] = v0 > 0.f ? v0 : 0.f;
            o[ft][1] = v1 > 0.f ? v1 : 0.f;
            o[ft][2] = v2 > 0.f ? v2 : 0.f;
            o[ft][3] = v3 > 0.f ? v3 : 0.f;
        }
    };

    const int base = grp ? 10 : 0;
    f32x4 Gh[2];
    bf16x4 bqM[2], bqH[2], bq9p[2];

    // ---- prologue (no barrier needed: all stores are later) ----
    {
        f32x4 T[2];
        if (grp == 0) {
            mfma_tile(18, T);                 // z299 = G18 row11 (node 299)
            int v = __shfl((int)pkbf2(T[0][3], T[1][3]), 32 + lm, 64);
            z[0] = unpk(v, 0); z[1] = unpk(v, 1);
            mfma_tile(9, T); pack(T, bq9p);   // epi8's Sn operand (held)
            Gh[0] = T[0]; Gh[1] = T[1];       // dummy init (unused at j1)
            bqM[0] = bq9p[0]; bqM[1] = bq9p[1];
            bqH[0] = bq9p[0]; bqH[1] = bq9p[1];
        } else {
            mfma_tile(0, T);                  // z0 = G0 row0 (node 0)
            int v = __shfl((int)pkbf2(T[0][0], T[1][0]), lm, 64);
            z[0] = unpk(v, 0); z[1] = unpk(v, 1);
            mfma_tile(8, T); pack(T, bqM);    // bq8 (epi9's Sp)
            mfma_tile(9, Gh); pack(Gh, bqH);  // G9/bq9 (epi'd at j1)
            bq9p[0] = bqM[0]; bq9p[1] = bqM[1];   // dummy
        }
    }

    // ---- main loop: 5 aligned barriers per store-pass ----
    for (int j = 1; j <= 5; ++j) {
        f32x4 Gc[2], Gd[2];
        bf16x4 bqC[2], bqD[2];
        if (j < 5) {
            int t0r = base + 2 * j - 2;
            mfma_tile(t0r,     Gc); pack(Gc, bqC);
            mfma_tile(t0r + 1, Gd); pack(Gd, bqD);
        } else {
            mfma_tile(base + 8, Gc); pack(Gc, bqC);
        }
        if (!POOL) __syncthreads();

        if (j == 1 && grp == 0) {             // tile 0 only
            float o[2][4];
            epi(Gc, bqC, bqC, bqD, 1, o);
            if (POOL) accum(o); else store_rows(0, o);
        } else if (j < 5) {                   // generic pair
            int Ta = base + 2 * j - 3;
            float o[2][4];
            epi(Gh, bqH, bqM, bqC, 0, o);
            if (POOL) accum(o); else store_rows(Ta, o);
            float o2[2][4];
            epi(Gc, bqC, bqH, bqD, 0, o2);
            if (POOL) accum(o2); else store_rows(Ta + 1, o2);
        } else {                              // j == 5
            float o[2][4];
            epi(Gh, bqH, bqM, bqC, 0, o);     // tile base+7
            if (POOL) accum(o); else store_rows(base + 7, o);
            if (grp == 0) {
                float o2[2][4];
                epi(Gc, bqC, bqH, bq9p, 0, o2);   // tile 8, next = bq9
                if (POOL) accum(o2); else store_rows(8, o2);
            } else {
                float o2[2][4];                   // tile 18 (rows 300+ invalid)
                epi(Gc, bqC, bqH, bqC, 2, o2);
                if (q < 3) { if (POOL) accum(o2); else store_rows(18, o2); }
            }
        }
        if (j < 5) {                          // rotate window
            Gh[0] = Gd[0]; Gh[1] = Gd[1];
            bqM[0] = bqC[0]; bqM[1] = bqC[1];
            bqH[0] = bqD[0]; bqH[1] = bqD[1];
        }
    }

    if (POOL) {
        #pragma unroll
        for (int ft = 0; ft < 2; ++ft) {
            psum[ft] += __shfl_xor(psum[ft], 16, 64);
            psum[ft] += __shfl_xor(psum[ft], 32, 64);
        }
        if (q == 0) {
            pool[grp * 128 + ftg0 * 16 + lm]      = psum[0];
            pool[grp * 128 + ftg0 * 16 + 16 + lm] = psum[1];
        }
    }
}

// One block (512 thr, 8 waves) per graph. LDS 80384 B (HW-proven 2/CU).
// 2-block threshold evidence: VGPR 60 ok (r9), 128 fails (r3). Live-set
// estimate here ~100-115; (512,2) caps at 128 (r2-verified semantics).
__global__ __launch_bounds__(512, 2) void k_graph(
        const float* __restrict__ x,
        const float* __restrict__ W1,  const float* __restrict__ b1,
        const float* __restrict__ b2v, const float* __restrict__ b3v,
        const float* __restrict__ fw1, const float* __restrict__ fb1,
        const float* __restrict__ fw2, const float* __restrict__ fb2,
        float* __restrict__ out) {
    __shared__ __align__(16) short buf[304 * HID];   // 77824 B, chunk-swizzled
    __shared__ __align__(16) float scr[640];         // 2560 B -> total 80384
    float* xs    = scr;          // 600 (layer-1 only, dead after)
    float* poolv = scr;          // 256 = pool(g0) | pool(g1)
    float* parts = scr + 256;    // 256
    float* s1    = scr + 512;    // 128

    const int g = blockIdx.x, tid = threadIdx.x;

    if (tid < 150) *(float4*)&xs[tid * 4] = *(const float4*)&x[g * 600 + tid * 4];
    __syncthreads();

    // ---- layer 1: buf <- relu(avg3(x) @ W1 + b1); rows 300..303 zeroed ----
    {
        const int kc1 = tid & 15;
        const int n0  = tid >> 4;            // 0..31
        float w1x[8], w1y[8], b1v[8];
        #pragma unroll
        for (int j = 0; j < 8; ++j) {
            w1x[j] = W1[kc1 * 8 + j];
            w1y[j] = W1[HID + kc1 * 8 + j];
            b1v[j] = b1[kc1 * 8 + j];
        }
        #pragma unroll
        for (int it = 0; it < 10; ++it) {
            int node = it * 32 + n0;         // 0..319
            if (node < 304) {
                uint32_t w[4] = {0u, 0u, 0u, 0u};
                if (node < P) {
                    int prev = (node == 0)     ? P - 1 : node - 1;
                    int next = (node == P - 1) ? 0     : node + 1;
                    float2 xp = *(const float2*)&xs[2 * prev];
                    float2 xc = *(const float2*)&xs[2 * node];
                    float2 xn = *(const float2*)&xs[2 * next];
                    float ax = (xp.x + xc.x + xn.x) * (1.f / 3.f);
                    float ay = (xp.y + xc.y + xn.y) * (1.f / 3.f);
                    #pragma unroll
                    for (int jj = 0; jj < 4; ++jj) {
                        float va = ax * w1x[2*jj]   + ay * w1y[2*jj]   + b1v[2*jj];
                        float vb = ax * w1x[2*jj+1] + ay * w1y[2*jj+1] + b1v[2*jj+1];
                        va = va > 0.f ? va : 0.f;
                        vb = vb > 0.f ? vb : 0.f;
                        w[jj] = pkbf2(va, vb);
                    }
                }
                *(uint4*)&buf[(node * 16 + (kc1 ^ (node & 15))) * 8] =
                    uint4{w[0], w[1], w[2], w[3]};
            }
        }
    }
    __syncthreads();

    run_pass<0>(buf, g_wsw,             b2v, poolv, tid);   // h1 -> h2 in place
    __syncthreads();
    run_pass<1>(buf, g_wsw + HID * HID, b3v, poolv, tid);   // h2 -> pooled sums
    __syncthreads();

    // ---- FC head (two-group pool: sum poolv[k] + poolv[128+k]) ----
    if (tid < 256) {
        int f = tid & 127, half = tid >> 7;
        float p = 0.f;
        const float* fw1c = fw1 + f;
        #pragma unroll 4
        for (int k = half * 64; k < half * 64 + 64; ++k)
            p += (poolv[k] + poolv[128 + k]) * fw1c[k * 128];
        parts[half * 128 + f] = p;
    }
    __syncthreads();
    if (tid < 128) {
        float o1 = fb1[tid] + (parts[tid] + parts[128 + tid]) * (1.0f / 300.0f);
        s1[tid] = o1 > 0.f ? o1 : 0.f;
    }
    __syncthreads();
    if (tid < 128) {
        int o = tid >> 6, ln = tid & 63;
        float v = s1[ln] * fw2[ln * 2 + o] + s1[ln + 64] * fw2[(ln + 64) * 2 + o];
        #pragma unroll
        for (int off = 1; off <= 32; off <<= 1)
            v += __shfl_xor(v, off, 64);
        if (ln == 0) out[g * 2 + o] = v + fb2[o];
    }
}

extern "C" void kernel_launch(void* const* d_in, const int* in_sizes, int n_in,
                              void* d_out, int out_size, void* d_ws, size_t ws_size,
                              hipStream_t stream) {
    const float* x   = (const float*)d_in[0];
    const float* W1  = (const float*)d_in[3];
    const float* b1  = (const float*)d_in[4];
    const float* W2  = (const float*)d_in[5];
    const float* b2  = (const float*)d_in[6];
    const float* W3  = (const float*)d_in[7];
    const float* b3  = (const float*)d_in[8];
    const float* fw1 = (const float*)d_in[9];
    const float* fb1 = (const float*)d_in[10];
    const float* fw2 = (const float*)d_in[11];
    const float* fb2 = (const float*)d_in[12];
    float* out = (float*)d_out;

    k_prep <<<dim3(16), dim3(256), 0, stream>>>(W2, W3);
    k_graph<<<dim3(NG), dim3(512), 0, stream>>>(x, W1, b1, b2, b3,
                                                fw1, fb1, fw2, fb2, out);
}

// Round 11
// 129.869 us; speedup vs baseline: 1.1295x; 1.1295x over previous
//
#include <hip/hip_runtime.h>
#include <hip/hip_bf16.h>
#include <stdint.h>

#define P    300
#define HID  128
#define NG   1000
#define NTL  19          // 16-node tiles (304 rows, 300 valid)

typedef __attribute__((ext_vector_type(8))) short bf16x8;
typedef __attribute__((ext_vector_type(4))) short bf16x4;
typedef __attribute__((ext_vector_type(4))) float f32x4;

// Swizzled bf16 W^T. Slot fkey holds weights for column perm(fkey):
// W2 (pass0): perm(fkey) = u*32 + 2*(fkey&15) + ((fkey>>4)&1), u=fkey>>5
//   -> computed feature IS the physical store position, so h2 is natural
//      and W3 (pass1) is natural. chunk(fkey,kc) at fkey*16+(kc^(fkey&15)).
__device__ short g_wsw[2 * HID * HID];

__device__ __forceinline__ short f2bf(float f) {
    union { float f; uint32_t u; } v; v.f = f;
    uint32_t r = v.u + 0x7fffu + ((v.u >> 16) & 1u);   // RNE
    return (short)(r >> 16);
}
__device__ __forceinline__ float bf2f(short s) {
    union { uint32_t u; float f; } v; v.u = ((uint32_t)(uint16_t)s) << 16;
    return v.f;
}
__device__ __forceinline__ uint32_t pkbf2(float a, float b) {   // low=a, high=b
    union { __hip_bfloat162 h; uint32_t u; } cv;
    cv.h = __float22bfloat162_rn(float2{a, b});
    return cv.u;
}
__device__ __forceinline__ float unpk(int v, int ft) {
    return bf2f((short)(ft ? (((uint32_t)v) >> 16) : (v & 0xffff)));
}

// K=16 bf16 MFMA as cross-lane "selector" (verified r5-r10).
__device__ __forceinline__ f32x4 mfma16(bf16x4 a, bf16x4 b, f32x4 c) {
#if __has_builtin(__builtin_amdgcn_mfma_f32_16x16x16bf16_1k)
    return __builtin_amdgcn_mfma_f32_16x16x16bf16_1k(a, b, c, 0, 0, 0);
#else
    asm("v_mfma_f32_16x16x16_bf16 %0, %1, %2, %0" : "+v"(c) : "v"(a), "v"(b));
    return c;
#endif
}

__global__ __launch_bounds__(256) void k_prep(const float* __restrict__ W2,
                                              const float* __restrict__ W3) {
    int b = blockIdx.x;                       // 16 blocks
    const bool perm = (b < 8);
    const float* W = perm ? W2 : W3;
    short* dst = g_wsw + (perm ? 0 : HID * HID);
    int t    = (b & 7) * 256 + threadIdx.x;   // 0..2047 chunks
    int fkey = t >> 4;
    int kc   = t & 15;
    int fsrc;
    if (perm) {
        int u = fkey >> 5, ft = (fkey >> 4) & 1, l = fkey & 15;
        fsrc = u * 32 + 2 * l + ft;
    } else fsrc = fkey;
    bf16x8 o;
    #pragma unroll
    for (int j = 0; j < 8; ++j)
        o[j] = f2bf(W[(kc * 8 + j) * HID + fsrc]);
    *(bf16x8*)&dst[(fkey * 16 + (kc ^ (fkey & 15))) * 8] = o;
}

// One GCN layer; 8 waves = 2 NODE groups x 4 waves, 2 ft-tiles/wave,
// ONE tile per barrier step (11 aligned steps) to keep the combined
// VGPR+AGPR live set <= ~95 -- the r10 lesson: 2-blocks/CU requires
// COMBINED regs <= 128/wave (r9: ~84 fits; r10: ~130 doesn't).
// LDS A-read redundancy 4x-ish (96 tile-reads/graph vs r9's 152).
//   g0 stores tiles 0..8:  pro rd{18->z299}; s1 rd9->bq9p;
//     s2..s10 rd 0..8; store T=s-3 at s=3..11 (T0 mode1).
//   g1 stores tiles 9..18: pro rd{0->z0, 8->bqM}; s1..s10 rd 9..18;
//     store T=s+7 at s=2..10; s11 store 18 (mode2, q<3).
// Race-proof (store(s) vs reads(>s), union of groups): stores(s_k) =
// {k-3, k+7}; reads(s_{k+1}) = {k-1, k+9} -- strictly ahead, disjoint.
// Boundary tiles: 18 read only in g0-pro/g1-s10, stored s11; 9 read
// only at s1 (both), stored s2; 0,8 read in g1-pro + g0 main, stored
// after. Same-step read/store separated by the barrier.
// Wraps: tile0 vp0(q==0) = z299 (G18 r11); tile18 vn3(q==2) = z0
// (G0 r0); zero pad rows 300..303 make the Sb/Sp spill terms inert.
template<int POOL>
__device__ __forceinline__ void run_pass(short* __restrict__ buf,
                                         const short* __restrict__ wbase,
                                         const float* __restrict__ bias,
                                         float* __restrict__ pool, int tid) {
    const int lane = tid & 63, wv = tid >> 6;
    const int grp = wv >> 2, w4 = wv & 3;
    const int q = lane >> 4, lm = lane & 15;
    const int ftg0 = w4 * 2;
    bf16x8 wf[2][4];
    #pragma unroll
    for (int ft = 0; ft < 2; ++ft) {
        int fkey = (ftg0 + ft) * 16 + lm;
        #pragma unroll
        for (int kk = 0; kk < 4; ++kk)
            wf[ft][kk] = *(const bf16x8*)&wbase[(fkey * 16 + ((4 * kk + q) ^ lm)) * 8];
    }
    float biaf[2];
    #pragma unroll
    for (int ft = 0; ft < 2; ++ft)
        biaf[ft] = POOL ? bias[(ftg0 + ft) * 16 + lm] : bias[w4 * 32 + 2 * lm + ft];
    const int fpair = w4 * 32 + 2 * lm;       // even physical feature (pass0)
    const int kcs = fpair >> 3, offs = fpair & 7;

    // selector A-fragments: A[m=lm][k=4q+j], entries bf16 1.0
    const short ONE = (short)0x3F80;
    bf16x4 Sb = {0, 0, 0, 0}, Sp = {0, 0, 0, 0}, Sn = {0, 0, 0, 0};
    #pragma unroll
    for (int j = 0; j < 4; ++j) {
        const int k = 4 * q + j;
        if (((lm & 3) == 0 && k == lm - 1) || ((lm & 3) == 3 && k == lm + 1))
            Sb[j] = ONE;
        if (lm == 0  && k == 15) Sp[j] = ONE;
        if (lm == 15 && k == 0 ) Sn[j] = ONE;
    }

    float psum[2] = {0.f, 0.f};
    float z[2];                               // wrap values (bf16-rounded)

    auto mfma_tile = [&](int t, f32x4 (&G)[2]) {
        const short* tb = buf + t * 2048;
        G[0] = f32x4{0.f, 0.f, 0.f, 0.f};
        G[1] = f32x4{0.f, 0.f, 0.f, 0.f};
        #pragma unroll
        for (int kk = 0; kk < 4; ++kk) {
            bf16x8 af = *(const bf16x8*)&tb[(lm * 16 + ((4 * kk + q) ^ lm)) * 8];
            G[0] = __builtin_amdgcn_mfma_f32_16x16x32_bf16(af, wf[0][kk], G[0], 0, 0, 0);
            G[1] = __builtin_amdgcn_mfma_f32_16x16x32_bf16(af, wf[1][kk], G[1], 0, 0, 0);
        }
    };
    auto pack = [&](const f32x4 (&G)[2], bf16x4 (&d)[2]) {
        #pragma unroll
        for (int ft = 0; ft < 2; ++ft) {
            union { bf16x4 v; uint32_t u[2]; } pk;
            pk.u[0] = pkbf2(G[ft][0], G[ft][1]);
            pk.u[1] = pkbf2(G[ft][2], G[ft][3]);
            d[ft] = pk.v;
        }
    };
    auto store_rows = [&](int T, float (&o)[2][4]) {
        #pragma unroll
        for (int i = 0; i < 4; ++i) {
            int node = T * 16 + q * 4 + i;
            *(uint32_t*)&buf[(node * 16 + (kcs ^ (node & 15))) * 8 + offs] =
                pkbf2(o[0][i], o[1][i]);
        }
    };
    auto accum = [&](float (&o)[2][4]) {
        #pragma unroll
        for (int ft = 0; ft < 2; ++ft)
            psum[ft] += o[ft][0] + o[ft][1] + o[ft][2] + o[ft][3];
    };

    // mode: 0 normal; 1 tile0 (skip Sp, +z at q==0 row0); 2 tile18
    // (skip Sn, +z at q==2 row11; caller guards q<3). Verified r10.
    auto epi = [&](const f32x4 (&E)[2], const bf16x4 (&bT)[2],
                   const bf16x4 (&bP)[2], const bf16x4 (&bN)[2],
                   int mode, float (&o)[2][4]) {
        #pragma unroll
        for (int ft = 0; ft < 2; ++ft) {
            f32x4 C = {0.f, 0.f, 0.f, 0.f};
            C = mfma16(Sb, bT[ft], C);
            if (mode != 1) C = mfma16(Sp, bP[ft], C);
            if (mode != 2) C = mfma16(Sn, bN[ft], C);
            const float s0 = E[ft][0] + E[ft][1];
            const float s2 = E[ft][2] + E[ft][3];
            float t0 = C[0] + s0;            // prev + G0 + G1
            float t1 = s0 + E[ft][2];
            float t2 = E[ft][1] + s2;
            float t3 = s2 + C[3];            // G2 + G3 + next
            if (mode == 1) t0 += (q == 0) ? z[ft] : 0.f;   // node299 wrap
            if (mode == 2) t3 += (q == 2) ? z[ft] : 0.f;   // node0 wrap
            float v0 = fmaf(t0, 1.f / 3.f, biaf[ft]);
            float v1 = fmaf(t1, 1.f / 3.f, biaf[ft]);
            float v2 = fmaf(t2, 1.f / 3.f, biaf[ft]);
            float v3 = fmaf(t3, 1.f / 3.f, biaf[ft]);
            o[ft][0] = v0 > 0.f ? v0 : 0.f;
            o[ft][1] = v1 > 0.f ? v1 : 0.f;
            o[ft][2] = v2 > 0.f ? v2 : 0.f;
            o[ft][3] = v3 > 0.f ? v3 : 0.f;
        }
    };

    f32x4 Gh[2], Gc[2];
    bf16x4 bqM[2], bqH[2], bqC[2], bq9p[2];

    // ---- prologue (no stores anywhere yet -> race-free) ----
    {
        f32x4 T[2];
        if (grp == 0) {
            mfma_tile(18, T);                 // z299 = G18 row11 (node 299)
            int v = __shfl((int)pkbf2(T[0][3], T[1][3]), 32 + lm, 64);
            z[0] = unpk(v, 0); z[1] = unpk(v, 1);
        } else {
            mfma_tile(0, T);                  // z0 = G0 row0 (node 0)
            int v = __shfl((int)pkbf2(T[0][0], T[1][0]), lm, 64);
            z[0] = unpk(v, 0); z[1] = unpk(v, 1);
            mfma_tile(8, T); pack(T, bqM);    // seed bq8 (Sp of tile 9)
            bqH[0] = bqM[0]; bqH[1] = bqM[1]; // s1 rotation -> bqM stays bq8
        }
    }

    // ---- 11 aligned barrier steps ----
    for (int s = 1; s <= 11; ++s) {
        const bool hasRead = (s <= 10);
        if (hasRead) {
            int rt = grp ? (8 + s) : ((s == 1) ? 9 : s - 2);
            mfma_tile(rt, Gc); pack(Gc, bqC);
        }
        if (!POOL) __syncthreads();

        if (grp == 0) {
            if (s == 1) {                     // pack-only hold of bq9
                bq9p[0] = bqC[0]; bq9p[1] = bqC[1];
                bqH[0] = bqC[0];  bqH[1] = bqC[1];   // init (T0 ignores bqM)
            } else if (s >= 3) {
                int T = s - 3;
                float o[2][4];
                if (s <= 10) epi(Gh, bqH, bqM, bqC,  (T == 0) ? 1 : 0, o);
                else         epi(Gh, bqH, bqM, bq9p, 0, o);   // T=8, next=bq9
                if (POOL) accum(o); else store_rows(T, o);
            }
        } else {
            if (s >= 2) {
                float o[2][4];
                if (s <= 10) {
                    epi(Gh, bqH, bqM, bqC, 0, o);
                    if (POOL) accum(o); else store_rows(7 + s, o);
                } else {                      // tile 18 (rows 300+ invalid)
                    epi(Gh, bqH, bqM, bqH, 2, o);   // bN unused in mode 2
                    if (q < 3) { if (POOL) accum(o); else store_rows(18, o); }
                }
            }
        }
        if (hasRead && !(grp == 0 && s == 1)) {   // rotate window
            Gh[0] = Gc[0];  Gh[1] = Gc[1];
            bqM[0] = bqH[0]; bqM[1] = bqH[1];
            bqH[0] = bqC[0]; bqH[1] = bqC[1];
        }
    }

    if (POOL) {
        #pragma unroll
        for (int ft = 0; ft < 2; ++ft) {
            psum[ft] += __shfl_xor(psum[ft], 16, 64);
            psum[ft] += __shfl_xor(psum[ft], 32, 64);
        }
        if (q == 0) {
            pool[grp * 128 + ftg0 * 16 + lm]      = psum[0];
            pool[grp * 128 + ftg0 * 16 + 16 + lm] = psum[1];
        }
    }
}

// One block (512 thr, 8 waves) per graph. LDS 80384 B (HW-proven 2/CU).
// 2-block gate: COMBINED VGPR+AGPR <= 128/wave (r9 fits at ~84, r10
// fails at ~130). This schedule's live set ~90. (512,2) caps arch at 128.
__global__ __launch_bounds__(512, 2) void k_graph(
        const float* __restrict__ x,
        const float* __restrict__ W1,  const float* __restrict__ b1,
        const float* __restrict__ b2v, const float* __restrict__ b3v,
        const float* __restrict__ fw1, const float* __restrict__ fb1,
        const float* __restrict__ fw2, const float* __restrict__ fb2,
        float* __restrict__ out) {
    __shared__ __align__(16) short buf[304 * HID];   // 77824 B, chunk-swizzled
    __shared__ __align__(16) float scr[640];         // 2560 B -> total 80384
    float* xs    = scr;          // 600 (layer-1 only, dead after)
    float* poolv = scr;          // 256 = pool(g0) | pool(g1)
    float* parts = scr + 256;    // 256
    float* s1    = scr + 512;    // 128

    const int g = blockIdx.x, tid = threadIdx.x;

    if (tid < 150) *(float4*)&xs[tid * 4] = *(const float4*)&x[g * 600 + tid * 4];
    __syncthreads();

    // ---- layer 1: buf <- relu(avg3(x) @ W1 + b1); rows 300..303 zeroed ----
    {
        const int kc1 = tid & 15;
        const int n0  = tid >> 4;            // 0..31
        float w1x[8], w1y[8], b1v[8];
        #pragma unroll
        for (int j = 0; j < 8; ++j) {
            w1x[j] = W1[kc1 * 8 + j];
            w1y[j] = W1[HID + kc1 * 8 + j];
            b1v[j] = b1[kc1 * 8 + j];
        }
        #pragma unroll
        for (int it = 0; it < 10; ++it) {
            int node = it * 32 + n0;         // 0..319
            if (node < 304) {
                uint32_t w[4] = {0u, 0u, 0u, 0u};
                if (node < P) {
                    int prev = (node == 0)     ? P - 1 : node - 1;
                    int next = (node == P - 1) ? 0     : node + 1;
                    float2 xp = *(const float2*)&xs[2 * prev];
                    float2 xc = *(const float2*)&xs[2 * node];
                    float2 xn = *(const float2*)&xs[2 * next];
                    float ax = (xp.x + xc.x + xn.x) * (1.f / 3.f);
                    float ay = (xp.y + xc.y + xn.y) * (1.f / 3.f);
                    #pragma unroll
                    for (int jj = 0; jj < 4; ++jj) {
                        float va = ax * w1x[2*jj]   + ay * w1y[2*jj]   + b1v[2*jj];
                        float vb = ax * w1x[2*jj+1] + ay * w1y[2*jj+1] + b1v[2*jj+1];
                        va = va > 0.f ? va : 0.f;
                        vb = vb > 0.f ? vb : 0.f;
                        w[jj] = pkbf2(va, vb);
                    }
                }
                *(uint4*)&buf[(node * 16 + (kc1 ^ (node & 15))) * 8] =
                    uint4{w[0], w[1], w[2], w[3]};
            }
        }
    }
    __syncthreads();

    run_pass<0>(buf, g_wsw,             b2v, poolv, tid);   // h1 -> h2 in place
    __syncthreads();
    run_pass<1>(buf, g_wsw + HID * HID, b3v, poolv, tid);   // h2 -> pooled sums
    __syncthreads();

    // ---- FC head (two-group pool: sum poolv[k] + poolv[128+k]) ----
    if (tid < 256) {
        int f = tid & 127, half = tid >> 7;
        float p = 0.f;
        const float* fw1c = fw1 + f;
        #pragma unroll 4
        for (int k = half * 64; k < half * 64 + 64; ++k)
            p += (poolv[k] + poolv[128 + k]) * fw1c[k * 128];
        parts[half * 128 + f] = p;
    }
    __syncthreads();
    if (tid < 128) {
        float o1 = fb1[tid] + (parts[tid] + parts[128 + tid]) * (1.0f / 300.0f);
        s1[tid] = o1 > 0.f ? o1 : 0.f;
    }
    __syncthreads();
    if (tid < 128) {
        int o = tid >> 6, ln = tid & 63;
        float v = s1[ln] * fw2[ln * 2 + o] + s1[ln + 64] * fw2[(ln + 64) * 2 + o];
        #pragma unroll
        for (int off = 1; off <= 32; off <<= 1)
            v += __shfl_xor(v, off, 64);
        if (ln == 0) out[g * 2 + o] = v + fb2[o];
    }
}

extern "C" void kernel_launch(void* const* d_in, const int* in_sizes, int n_in,
                              void* d_out, int out_size, void* d_ws, size_t ws_size,
                              hipStream_t stream) {
    const float* x   = (const float*)d_in[0];
    const float* W1  = (const float*)d_in[3];
    const float* b1  = (const float*)d_in[4];
    const float* W2  = (const float*)d_in[5];
    const float* b2  = (const float*)d_in[6];
    const float* W3  = (const float*)d_in[7];
    const float* b3  = (const float*)d_in[8];
    const float* fw1 = (const float*)d_in[9];
    const float* fb1 = (const float*)d_in[10];
    const float* fw2 = (const float*)d_in[11];
    const float* fb2 = (const float*)d_in[12];
    float* out = (float*)d_out;

    k_prep <<<dim3(16), dim3(256), 0, stream>>>(W2, W3);
    k_graph<<<dim3(NG), dim3(512), 0, stream>>>(x, W1, b1, b2, b3,
                                                fw1, fb1, fw2, fb2, out);
}

// Round 13
// 121.564 us; speedup vs baseline: 1.2066x; 1.0683x over previous
//
#include <hip/hip_runtime.h>
#include <hip/hip_bf16.h>
#include <stdint.h>

#define P    300
#define HID  128
#define NG   1000
#define NTL  19          // 16-node tiles (304 rows, 300 valid)

typedef __attribute__((ext_vector_type(8))) short bf16x8;
typedef __attribute__((ext_vector_type(4))) float f32x4;

// Swizzled bf16 W^T, NATURAL feature order both layers (1-ft/wave needs
// no store-pairing permutation). chunk(fkey,kc) at fkey*16+(kc^(fkey&15)).
__device__ short g_wsw[2 * HID * HID];

__device__ __forceinline__ short f2bf(float f) {
    union { float f; uint32_t u; } v; v.f = f;
    uint32_t r = v.u + 0x7fffu + ((v.u >> 16) & 1u);   // RNE
    return (short)(r >> 16);
}
__device__ __forceinline__ uint32_t pkbf2(float a, float b) {   // low=a, high=b
    union { __hip_bfloat162 h; uint32_t u; } cv;
    cv.h = __float22bfloat162_rn(float2{a, b});
    return cv.u;
}

__global__ __launch_bounds__(256) void k_prep(const float* __restrict__ W2,
                                              const float* __restrict__ W3) {
    int b = blockIdx.x;                       // 16 blocks
    const float* W = (b < 8) ? W2 : W3;
    short* dst = g_wsw + ((b < 8) ? 0 : HID * HID);
    int t    = (b & 7) * 256 + threadIdx.x;   // 0..2047 chunks
    int fkey = t >> 4;
    int kc   = t & 15;
    bf16x8 o;
    #pragma unroll
    for (int j = 0; j < 8; ++j)
        o[j] = f2bf(W[(kc * 8 + j) * HID + fkey]);
    *(bf16x8*)&dst[(fkey * 16 + (kc ^ (fkey & 15))) * 8] = o;
}

// ring-average + bias + relu over 4 consecutive node-rows (f32 in regs)
__device__ __forceinline__ void avg_epi(const f32x4 &G, float vp0, float vn3,
                                        float b, float* o) {
    o[0] = (vp0  + G[0] + G[1]) * (1.0f / 3.0f) + b;
    o[1] = (G[0] + G[1] + G[2]) * (1.0f / 3.0f) + b;
    o[2] = (G[1] + G[2] + G[3]) * (1.0f / 3.0f) + b;
    o[3] = (G[2] + G[3] + vn3 ) * (1.0f / 3.0f) + b;
    #pragma unroll
    for (int i = 0; i < 4; ++i) o[i] = o[i] > 0.f ? o[i] : 0.f;
}

// One GCN layer; 8 waves, wave wv owns ft-tile wv (1 ft-tile = 16
// features; fkey = wv*16+lm). Feature-split = zero duplicated MFMAs;
// r11 falsified LDS-traffic as the binding constraint, so the 2x A-read
// redundancy is acceptable. Per-wave work is HALF of r4's best-known
// (2-ft) structure; waves/SIMD double to 4 to hide ds_read/shuffle
// latency that 2/SIMD could not (r4/r7/r9 all ~53 us).
// 3-PHASE / 2-BARRIER schedule (r4-proven race-free):
//   A: MFMA tiles {10..18, 0} -> GH (reads only); barrier
//   B: i=0..8: MFMA tile 9-i -> GL[i]; epi/store tiles 10..18, 0
//      (reads {9..1} vs stores {10..18,0}: DISJOINT); barrier
//   C: epi/store tiles 1..9 (stores only)
// Epilogue: RAW-F32 shuffles (no pack/unpack -- 1 ft/wave ships one
// float per shuffle): vA = row above / r15-carry, vB = row below,
// vC = next-tile r0. Wraps: tile0.vp0(q0) = G18 r11 (lane 32+lm),
// tile18.vn3(q2) = G0 r0, tile0.vn3(q3) = G1 r0. Neighbors are now
// f32-exact (previously bf16-rounded) -> closer to the f32 reference.
// Stores: b16 per feature via pkbf2 pairs + shr (r9's f2bf was 4 VALU
// per element; this is ~1.5).
template<int POOL>
__device__ __forceinline__ void run_pass(short* __restrict__ buf,
                                         const short* __restrict__ wbase,
                                         const float* __restrict__ bias,
                                         float* __restrict__ pool, int tid) {
    const int lane = tid & 63, wv = tid >> 6, q = lane >> 4, lm = lane & 15;
    const int fkey = wv * 16 + lm;            // this lane's feature
    bf16x8 wf[4];
    #pragma unroll
    for (int kk = 0; kk < 4; ++kk)
        wf[kk] = *(const bf16x8*)&wbase[(fkey * 16 + ((4 * kk + q) ^ lm)) * 8];
    const float biaf = bias[fkey];
    const int kcs = fkey >> 3, offs = fkey & 7;
    const int sA = (q == 0) ? (48 + lm) : (lane - 16);  // r15 carry / row above
    const int sB = (lane + 16) & 63;                    // row below (q<3)

    float psum = 0.f;

    auto mfma_tile = [&](int t, f32x4 &G) {
        const short* tb = buf + t * 2048;
        G = f32x4{0.f, 0.f, 0.f, 0.f};
        #pragma unroll
        for (int kk = 0; kk < 4; ++kk) {
            bf16x8 af = *(const bf16x8*)&tb[(lm * 16 + ((4 * kk + q) ^ lm)) * 8];
            G = __builtin_amdgcn_mfma_f32_16x16x32_bf16(af, wf[kk], G, 0, 0, 0);
        }
    };
    auto store_rows = [&](int T, float (&o)[4]) {
        uint32_t u01 = pkbf2(o[0], o[1]);
        uint32_t u23 = pkbf2(o[2], o[3]);
        int n0 = T * 16 + q * 4;
        buf[(n0 * 16       + (kcs ^ ( n0      & 15))) * 8 + offs] = (short)u01;
        buf[((n0 + 1) * 16 + (kcs ^ ((n0 + 1) & 15))) * 8 + offs] = (short)(u01 >> 16);
        buf[((n0 + 2) * 16 + (kcs ^ ((n0 + 2) & 15))) * 8 + offs] = (short)u23;
        buf[((n0 + 3) * 16 + (kcs ^ ((n0 + 3) & 15))) * 8 + offs] = (short)(u23 >> 16);
    };
    auto accum = [&](float (&o)[4]) { psum += o[0] + o[1] + o[2] + o[3]; };

    float c15;
    // mid-ring epilogue of tile with centers E; N0 = next tile's G[0]
    auto epi_mid = [&](const f32x4 &E, float N0, float (&o)[4]) {
        float vA = __shfl(E[3], sA, 64);
        float vB = __shfl(E[0], sB, 64);
        float vC = __shfl(N0, lm, 64);
        float vp0 = (q == 0) ? c15 : vA;
        float vn3 = (q == 3) ? vC : vB;
        avg_epi(E, vp0, vn3, biaf, o);
        c15 = vA;                 // this tile's r15 -> next tile's vp0(q==0)
    };

    f32x4 GH[10];   // GH[k] = G[10+k] for k<9; GH[9] = G[0]
    f32x4 GL[9];    // GL[i] = G[9-i]

    // ---- phase A: MFMA tiles 10..18 and 0 (reads only) ----
    #pragma unroll
    for (int k = 0; k < 9; ++k) mfma_tile(10 + k, GH[k]);
    mfma_tile(0, GH[9]);
    if (!POOL) __syncthreads();

    // ---- phase B: MFMA 9..1 interleaved with epi/store of 10..18, 0 ----
    #pragma unroll
    for (int i = 0; i < 9; ++i) {
        mfma_tile(9 - i, GL[i]);
        if (i == 0) c15 = __shfl(GL[0][3], 48 + lm, 64);   // G9 r15 (node 159)
        if (i < 8) {
            float o[4];
            epi_mid(GH[i], GH[i + 1][0], o);
            if (POOL) accum(o); else store_rows(10 + i, o);
        } else {
            // tile 18 (rows 288..299 valid; row299.next = node0)
            float o18[4];
            {
                float vA = __shfl(GH[8][3], sA, 64);
                float vB = __shfl(GH[8][0], sB, 64);
                float vZ = __shfl(GH[9][0], lm, 64);       // G0 r0 (node 0)
                float vp0 = (q == 0) ? c15 : vA;
                float vn3 = (q == 2) ? vZ : vB;
                avg_epi(GH[8], vp0, vn3, biaf, o18);
            }
            if (q < 3) { if (POOL) accum(o18); else store_rows(18, o18); }
            // tile 0 (row0.prev = node299 = G18 r11; row15.next = G1 r0)
            float o0[4];
            {
                float vA0 = __shfl(GH[9][3], (lane - 16) & 63, 64);
                float vB0 = __shfl(GH[9][0], sB, 64);
                float vP  = __shfl(GH[8][3], 32 + lm, 64); // G18 r11 (node 299)
                float vN  = __shfl(GL[8][0], lm, 64);      // G1 r0 (node 16)
                float vp0 = (q == 0) ? vP : vA0;
                float vn3 = (q == 3) ? vN : vB0;
                avg_epi(GH[9], vp0, vn3, biaf, o0);
            }
            if (POOL) accum(o0); else store_rows(0, o0);
        }
    }
    if (!POOL) __syncthreads();

    // ---- phase C: epi/store tiles 1..9 (stores only) ----
    c15 = __shfl(GH[9][3], 48 + lm, 64);                   // G0 r15 (node 15)
    #pragma unroll
    for (int T = 1; T <= 9; ++T) {
        float o[4];
        float N0 = (T < 9) ? GL[8 - T][0] : GH[0][0];      // next tile's r0
        epi_mid(GL[9 - T], N0, o);
        if (POOL) accum(o); else store_rows(T, o);
    }

    if (POOL) {
        psum += __shfl_xor(psum, 16, 64);
        psum += __shfl_xor(psum, 32, 64);
        if (q == 0) pool[fkey] = psum;
    }
}

// One block (512 thr, 8 waves) per graph, feature-split. LDS 80384 B
// (HW-proven 2/CU) -> 16 waves/CU = 4 waves/SIMD. Register gate (r9/r10
// evidence): 2 blocks/CU needs COMBINED VGPR+AGPR <= 128/wave. Live set:
// GH+GL 76 + wf 16 + temps ~25 = ~117. (512,2) caps arch at 128.
__global__ __launch_bounds__(512, 2) void k_graph(
        const float* __restrict__ x,
        const float* __restrict__ W1,  const float* __restrict__ b1,
        const float* __restrict__ b2v, const float* __restrict__ b3v,
        const float* __restrict__ fw1, const float* __restrict__ fb1,
        const float* __restrict__ fw2, const float* __restrict__ fb2,
        float* __restrict__ out) {
    __shared__ __align__(16) short buf[304 * HID];   // 77824 B, chunk-swizzled
    __shared__ __align__(16) float scr[640];         // 2560 B -> total 80384
    float* xs    = scr;          // 600 (layer-1 only, dead after)
    float* pool  = scr;          // 128
    float* parts = scr + 128;    // 256
    float* s1    = scr + 384;    // 128

    const int g = blockIdx.x, tid = threadIdx.x;

    if (tid < 150) *(float4*)&xs[tid * 4] = *(const float4*)&x[g * 600 + tid * 4];
    __syncthreads();

    // ---- layer 1: buf <- relu(avg3(x) @ W1 + b1); rows 300..303 zeroed ----
    {
        const int kc1 = tid & 15;
        const int n0  = tid >> 4;            // 0..31
        float w1x[8], w1y[8], b1v[8];
        #pragma unroll
        for (int j = 0; j < 8; ++j) {
            w1x[j] = W1[kc1 * 8 + j];
            w1y[j] = W1[HID + kc1 * 8 + j];
            b1v[j] = b1[kc1 * 8 + j];
        }
        #pragma unroll
        for (int it = 0; it < 10; ++it) {
            int node = it * 32 + n0;         // 0..319
            if (node < 304) {
                uint32_t w[4] = {0u, 0u, 0u, 0u};
                if (node < P) {
                    int prev = (node == 0)     ? P - 1 : node - 1;
                    int next = (node == P - 1) ? 0     : node + 1;
                    float2 xp = *(const float2*)&xs[2 * prev];
                    float2 xc = *(const float2*)&xs[2 * node];
                    float2 xn = *(const float2*)&xs[2 * next];
                    float ax = (xp.x + xc.x + xn.x) * (1.f / 3.f);
                    float ay = (xp.y + xc.y + xn.y) * (1.f / 3.f);
                    #pragma unroll
                    for (int jj = 0; jj < 4; ++jj) {
                        float va = ax * w1x[2*jj]   + ay * w1y[2*jj]   + b1v[2*jj];
                        float vb = ax * w1x[2*jj+1] + ay * w1y[2*jj+1] + b1v[2*jj+1];
                        va = va > 0.f ? va : 0.f;
                        vb = vb > 0.f ? vb : 0.f;
                        w[jj] = pkbf2(va, vb);
                    }
                }
                *(uint4*)&buf[(node * 16 + (kc1 ^ (node & 15))) * 8] =
                    uint4{w[0], w[1], w[2], w[3]};
            }
        }
    }
    __syncthreads();

    run_pass<0>(buf, g_wsw,             b2v, pool, tid);   // h1 -> h2 in place
    __syncthreads();
    run_pass<1>(buf, g_wsw + HID * HID, b3v, pool, tid);   // h2 -> pooled sums
    __syncthreads();

    // ---- FC head (tiny; 256 active threads) ----
    if (tid < 256) {
        int f = tid & 127, half = tid >> 7;
        float p = 0.f;
        const float* fw1c = fw1 + f;
        #pragma unroll 4
        for (int k = half * 64; k < half * 64 + 64; ++k)
            p += pool[k] * fw1c[k * 128];
        parts[half * 128 + f] = p;
    }
    __syncthreads();
    if (tid < 128) {
        float o1 = fb1[tid] + (parts[tid] + parts[128 + tid]) * (1.0f / 300.0f);
        s1[tid] = o1 > 0.f ? o1 : 0.f;
    }
    __syncthreads();
    if (tid < 128) {
        int o = tid >> 6, ln = tid & 63;
        float v = s1[ln] * fw2[ln * 2 + o] + s1[ln + 64] * fw2[(ln + 64) * 2 + o];
        #pragma unroll
        for (int off = 1; off <= 32; off <<= 1)
            v += __shfl_xor(v, off, 64);
        if (ln == 0) out[g * 2 + o] = v + fb2[o];
    }
}

extern "C" void kernel_launch(void* const* d_in, const int* in_sizes, int n_in,
                              void* d_out, int out_size, void* d_ws, size_t ws_size,
                              hipStream_t stream) {
    const float* x   = (const float*)d_in[0];
    const float* W1  = (const float*)d_in[3];
    const float* b1  = (const float*)d_in[4];
    const float* W2  = (const float*)d_in[5];
    const float* b2  = (const float*)d_in[6];
    const float* W3  = (const float*)d_in[7];
    const float* b3  = (const float*)d_in[8];
    const float* fw1 = (const float*)d_in[9];
    const float* fb1 = (const float*)d_in[10];
    const float* fw2 = (const float*)d_in[11];
    const float* fb2 = (const float*)d_in[12];
    float* out = (float*)d_out;

    k_prep <<<dim3(16), dim3(256), 0, stream>>>(W2, W3);
    k_graph<<<dim3(NG), dim3(512), 0, stream>>>(x, W1, b1, b2, b3,
                                                fw1, fb1, fw2, fb2, out);
}